// Round 2
// baseline (463.323 us; speedup 1.0000x reference)
//
#include <hip/hip_runtime.h>

// ---------------- types / helpers ----------------
typedef __attribute__((ext_vector_type(8))) __bf16 bf16x8;
typedef __attribute__((ext_vector_type(8))) short short8;
typedef __attribute__((ext_vector_type(4))) float f32x4;

static __device__ __forceinline__ unsigned short f2bf(float f) {
    unsigned u = __float_as_uint(f);
    u += 0x7FFFu + ((u >> 16) & 1u);
    return (unsigned short)(u >> 16);
}
static __device__ __forceinline__ unsigned cvt_pk_bf16(float lo, float hi) {
    unsigned r;
    asm("v_cvt_pk_bf16_f32 %0, %1, %2" : "=v"(r) : "v"(lo), "v"(hi));
    return r;
}
static __device__ __forceinline__ bf16x8 as_bf16x8(short8 v) {
    return __builtin_bit_cast(bf16x8, v);
}

// problem sizes
#define NB 8
#define NS 5
#define NQ 15
// ws layout (in floats)
#define A_ROWS (NB*NS*16)          // 640
#define B_ROWS (NB*NQ*16)          // 1920
#define A_OFF_F 0
#define B_OFF_F (A_ROWS*256)                     // 163840
#define XF_OFF_F (B_OFF_F + B_ROWS*256)          // 655360
#define WF_OFF_BYTES ((XF_OFF_F + 600*512)*4)    // 3850240 (16B aligned)

// ---------------- kernel 1: precompute A (sup@W1a + b1) and B (qry@W1b) ----------------
// grid = 40 + 120 blocks (one per cell), 512 threads. Stage the cell's 4096
// floats in LDS once; each thread computes 8 outputs (one col, 8 spatial n).
__global__ void k1_rows(const float* __restrict__ sup, const float* __restrict__ qry,
                        const float* __restrict__ gw1, const float* __restrict__ gb1,
                        float* __restrict__ ws) {
    __shared__ float x[258 * 16];
    int cid = blockIdx.x;
    bool isA = (cid < NB * NS);
    int cell = isA ? cid : (cid - NB * NS);
    const float* src = (isA ? sup : qry) + (size_t)cell * 4096;
    int t = threadIdx.x;
    // stage 4096 floats: x[k*16 + n]
    ((float4*)x)[t] = ((const float4*)src)[t];
    ((float4*)x)[t + 512] = ((const float4*)src)[t + 512];
    if (t < 16) {
        x[256 * 16 + t] = (float)(t >> 2) * 0.25f;
        x[257 * 16 + t] = (float)(t & 3) * 0.25f;
    }
    __syncthreads();
    int col = t & 255, nh = t >> 8;   // nh selects n in [nh*8, nh*8+8)
    float acc[8];
    float binit = isA ? gb1[col] : 0.0f;
    #pragma unroll
    for (int j = 0; j < 8; ++j) acc[j] = binit;
    int koff = isA ? 0 : 258;
    for (int k = 0; k < 258; ++k) {
        float wv = gw1[(size_t)(koff + k) * 256 + col];
        const float4* xr = (const float4*)(x + k * 16 + nh * 8);
        float4 a = xr[0], b2 = xr[1];
        acc[0] += a.x * wv;  acc[1] += a.y * wv;
        acc[2] += a.z * wv;  acc[3] += a.w * wv;
        acc[4] += b2.x * wv; acc[5] += b2.y * wv;
        acc[6] += b2.z * wv; acc[7] += b2.w * wv;
    }
    float* dst = ws + (isA ? A_OFF_F : B_OFF_F) + ((size_t)cell * 16 + nh * 8) * 256 + col;
    #pragma unroll
    for (int j = 0; j < 8; ++j) dst[(size_t)j * 256] = acc[j];
}

// ---------------- kernel 2: weights g_w2/3/4 -> bf16 fragment-linear layout ----------------
// layout: wf[((layer*16 + ntile)*8 + kk)*64 + lane][8]
//   holds W[k][n], n = ntile*16 + (lane&15), k = kk*32 + (lane>>4)*8 + j
__global__ void k2_wfrag(const float* __restrict__ w2, const float* __restrict__ w3,
                         const float* __restrict__ w4, unsigned short* __restrict__ wf) {
    int bid = blockIdx.x;
    int layer = bid >> 7;
    int rem = bid & 127;
    int ntile = rem >> 3;
    int kk = rem & 7;
    int l = threadIdx.x;
    const float* W = (layer == 0) ? w2 : ((layer == 1) ? w3 : w4);
    int nn = ntile * 16 + (l & 15);
    int k0 = kk * 32 + (l >> 4) * 8;
    short8 ov;
    #pragma unroll
    for (int j = 0; j < 8; ++j)
        ov[j] = (short)f2bf(W[(size_t)(k0 + j) * 256 + nn]);
    *(short8*)(wf + ((size_t)bid * 64 + l) * 8) = ov;
}

// ---------------- kernel 3: g-MLP layers 2..4 + pair-sum ----------------
// grid = 600*2 blocks (bqs, 128-row half), 256 threads (4 waves).
// waves split N (64 cols each); each wave computes 128 rows x 64 cols (8mm x 4tt).
// H is a single in-place 64KB buffer: all reads of layer L complete before the
// post-barrier epilogue writes layer L+1 into the same buffer.
__launch_bounds__(256, 2)
__global__ void k3_g(const float* __restrict__ wsA, const float* __restrict__ wsB,
                     const unsigned short* __restrict__ wf,
                     const float* __restrict__ gb2, const float* __restrict__ gb3,
                     const float* __restrict__ gb4, float* __restrict__ xf) {
    __shared__ short H[128 * 256];   // 64KB bf16, XOR-swizzled rows (stride 512B)
    int bid = blockIdx.x;
    int bqs = bid >> 1, half = bid & 1;
    int b = bqs / 75, rem = bqs % 75, qi = rem / 5, si = rem % 5;
    int t = threadIdx.x;
    int w = t >> 6, l = t & 63;
    char* Hc = (char*)H;

    // ---- phase 1: H1[p,f] = relu(A[n,f] + B[m,f]); p = half*128 + lr, m=p>>4, n=p&15
    // thread owns cols c0=2*(t&127),c0+1 and rows 64*(t>>7)..+64; b32 packed writes.
    {
        int c0 = 2 * (t & 127);
        int r0 = 64 * (t >> 7);
        const float2* Arow = (const float2*)(wsA + (size_t)(b * NS + si) * 4096 + c0);
        const float2* Brow = (const float2*)(wsB + ((size_t)(b * NQ + qi) * 16 + half * 8) * 256 + c0);
        float2 Av[16], Bv[8];
        #pragma unroll
        for (int n = 0; n < 16; ++n) Av[n] = Arow[n * 128];
        #pragma unroll
        for (int m = 0; m < 8; ++m) Bv[m] = Brow[m * 128];
        for (int i = 0; i < 64; ++i) {
            int lr = r0 + i;
            float2 a = Av[lr & 15], bb = Bv[lr >> 4];
            float lo = a.x + bb.x; lo = lo > 0.f ? lo : 0.f;
            float hi = a.y + bb.y; hi = hi > 0.f ? hi : 0.f;
            *(unsigned*)(Hc + lr * 512 + ((2 * c0) ^ ((lr & 7) << 4))) = cvt_pk_bf16(lo, hi);
        }
    }
    __syncthreads();

    for (int L = 0; L < 3; ++L) {
        const unsigned short* Wl = wf + (size_t)L * 65536;
        const float* bias = (L == 0) ? gb2 : ((L == 1) ? gb3 : gb4);
        f32x4 acc[8][4];
        #pragma unroll
        for (int mm = 0; mm < 8; ++mm)
            #pragma unroll
            for (int tt = 0; tt < 4; ++tt)
                acc[mm][tt] = (f32x4){0.f, 0.f, 0.f, 0.f};

        #pragma unroll
        for (int kk = 0; kk < 8; ++kk) {
            short8 af[8];
            int kb = kk * 64 + (l >> 4) * 16;
            #pragma unroll
            for (int mm = 0; mm < 8; ++mm) {
                int row = mm * 16 + (l & 15);
                af[mm] = *(const short8*)(Hc + row * 512 + (kb ^ ((row & 7) << 4)));
            }
            #pragma unroll
            for (int tt = 0; tt < 4; ++tt) {
                int ntile = w * 4 + tt;
                short8 bv = *(const short8*)(Wl + (((size_t)ntile * 8 + kk) * 64 + l) * 8);
                #pragma unroll
                for (int mm = 0; mm < 8; ++mm)
                    acc[mm][tt] = __builtin_amdgcn_mfma_f32_16x16x32_bf16(
                        as_bf16x8(af[mm]), as_bf16x8(bv), acc[mm][tt], 0, 0, 0);
            }
        }
        __syncthreads();   // all reads of H done; safe to overwrite in place

        if (L < 2) {
            #pragma unroll
            for (int tt = 0; tt < 4; ++tt) {
                int c = w * 64 + tt * 16 + (l & 15);
                float bvv = bias[c];
                #pragma unroll
                for (int mm = 0; mm < 8; ++mm) {
                    #pragma unroll
                    for (int r = 0; r < 4; ++r) {
                        int row = mm * 16 + (l >> 4) * 4 + r;
                        float v = acc[mm][tt][r] + bvv;
                        v = v > 0.f ? v : 0.f;
                        float vh = __shfl_xor(v, 1);
                        if (!(l & 1)) {
                            *(unsigned*)(Hc + row * 512 + ((2 * c) ^ ((row & 7) << 4))) =
                                cvt_pk_bf16(v, vh);
                        }
                    }
                }
            }
            __syncthreads();
        } else {
            // layer 4: relu + column-sum over this half's 128 rows -> xf[bqs][half][c]
            #pragma unroll
            for (int tt = 0; tt < 4; ++tt) {
                int c = w * 64 + tt * 16 + (l & 15);
                float bvv = bias[c];
                float s = 0.0f;
                #pragma unroll
                for (int mm = 0; mm < 8; ++mm)
                    #pragma unroll
                    for (int r = 0; r < 4; ++r) {
                        float v = acc[mm][tt][r] + bvv;
                        s += (v > 0.f ? v : 0.f);
                    }
                s += __shfl_xor(s, 16);
                s += __shfl_xor(s, 32);
                if (l < 16)
                    xf[(size_t)bqs * 512 + half * 256 + c - (l & 15) + l] = s;
            }
        }
    }
}

// ---------------- kernel 4: f-MLP + sigmoid + MSE loss ----------------
// grid = 150 blocks x 4 cells, 256 threads; fw loads reused 4x.
__global__ void k4_f(const float* __restrict__ xf,
                     const float* __restrict__ fw1, const float* __restrict__ fb1,
                     const float* __restrict__ fw2, const float* __restrict__ fb2,
                     const float* __restrict__ fw3, const float* __restrict__ fb3,
                     const float* __restrict__ fw4, const float* __restrict__ fb4,
                     const int* __restrict__ sy, const int* __restrict__ qy,
                     float* __restrict__ out) {
    __shared__ float xb[4][256], yb[4][256], y3[4][32];
    int base = blockIdx.x * 4;
    int t = threadIdx.x;
    #pragma unroll
    for (int c = 0; c < 4; ++c)
        xb[c][t] = xf[(size_t)(base + c) * 512 + t] + xf[(size_t)(base + c) * 512 + 256 + t];
    __syncthreads();
    float acc[4];
    #pragma unroll
    for (int c = 0; c < 4; ++c) acc[c] = fb1[t];
    for (int k = 0; k < 256; ++k) {
        float wv = fw1[(size_t)k * 256 + t];
        #pragma unroll
        for (int c = 0; c < 4; ++c) acc[c] += xb[c][k] * wv;
    }
    #pragma unroll
    for (int c = 0; c < 4; ++c) yb[c][t] = acc[c] > 0.f ? acc[c] : 0.f;
    __syncthreads();
    #pragma unroll
    for (int c = 0; c < 4; ++c) acc[c] = fb2[t];
    for (int k = 0; k < 256; ++k) {
        float wv = fw2[(size_t)k * 256 + t];
        #pragma unroll
        for (int c = 0; c < 4; ++c) acc[c] += yb[c][k] * wv;
    }
    #pragma unroll
    for (int c = 0; c < 4; ++c) xb[c][t] = acc[c] > 0.f ? acc[c] : 0.f;
    __syncthreads();
    if (t < 116) {
        int c = t / 29, col = t % 29;
        float a = fb3[col];
        for (int k = 0; k < 256; ++k) a += xb[c][k] * fw3[(size_t)k * 29 + col];
        y3[c][col] = a > 0.f ? a : 0.f;
    }
    __syncthreads();
    if (t < 4) {
        int c = t;
        float z = fb4[0];
        for (int k = 0; k < 29; ++k) z += y3[c][k] * fw4[k];
        float score = 1.0f / (1.0f + __expf(-z));
        int bqs = base + c;
        int b = bqs / 75, rem = bqs % 75, qi = rem / 5, si = rem % 5;
        float label = (sy[b * NS + si] == qy[b * NQ + qi]) ? 1.0f : 0.0f;
        float d = label - score;
        atomicAdd(out, d * d * 0.125f);
    }
}

// ---------------- launch ----------------
extern "C" void kernel_launch(void* const* d_in, const int* in_sizes, int n_in,
                              void* d_out, int out_size, void* d_ws, size_t ws_size,
                              hipStream_t stream) {
    const float* sup = (const float*)d_in[0];
    const float* qry = (const float*)d_in[1];
    const int*   sy  = (const int*)d_in[2];
    const int*   qy  = (const int*)d_in[3];
    const float* gw1 = (const float*)d_in[4];
    const float* gb1 = (const float*)d_in[5];
    const float* gw2 = (const float*)d_in[6];
    const float* gb2 = (const float*)d_in[7];
    const float* gw3 = (const float*)d_in[8];
    const float* gb3 = (const float*)d_in[9];
    const float* gw4 = (const float*)d_in[10];
    const float* gb4 = (const float*)d_in[11];
    const float* fw1 = (const float*)d_in[12];
    const float* fb1 = (const float*)d_in[13];
    const float* fw2 = (const float*)d_in[14];
    const float* fb2 = (const float*)d_in[15];
    const float* fw3 = (const float*)d_in[16];
    const float* fb3 = (const float*)d_in[17];
    const float* fw4 = (const float*)d_in[18];
    const float* fb4 = (const float*)d_in[19];

    float* ws = (float*)d_ws;
    float* A  = ws + A_OFF_F;
    float* B  = ws + B_OFF_F;
    float* xf = ws + XF_OFF_F;
    unsigned short* wf = (unsigned short*)((char*)d_ws + WF_OFF_BYTES);
    float* out = (float*)d_out;

    hipMemsetAsync(out, 0, sizeof(float), stream);

    k1_rows<<<NB * NS + NB * NQ, 512, 0, stream>>>(sup, qry, gw1, gb1, ws);
    k2_wfrag<<<384, 64, 0, stream>>>(gw2, gw3, gw4, wf);
    k3_g<<<600 * 2, 256, 0, stream>>>(A, B, wf, gb2, gb3, gb4, xf);
    k4_f<<<150, 256, 0, stream>>>(xf, fw1, fb1, fw2, fb2, fw3, fb3, fw4, fb4, sy, qy, out);
}

// Round 3
// 184.347 us; speedup vs baseline: 2.5133x; 2.5133x over previous
//
#include <hip/hip_runtime.h>

// ---------------- types / helpers ----------------
typedef __attribute__((ext_vector_type(8))) __bf16 bf16x8;
typedef __attribute__((ext_vector_type(8))) short short8;
typedef __attribute__((ext_vector_type(4))) float f32x4;

static __device__ __forceinline__ unsigned short f2bf(float f) {
    unsigned u = __float_as_uint(f);
    u += 0x7FFFu + ((u >> 16) & 1u);
    return (unsigned short)(u >> 16);
}
static __device__ __forceinline__ unsigned cvt_pk_bf16(float lo, float hi) {
    unsigned r;
    asm("v_cvt_pk_bf16_f32 %0, %1, %2" : "=v"(r) : "v"(lo), "v"(hi));
    return r;
}
static __device__ __forceinline__ bf16x8 as_bf16x8(short8 v) {
    return __builtin_bit_cast(bf16x8, v);
}

// problem sizes
#define NB 8
#define NS 5
#define NQ 15
// ws layout (in floats)
#define A_OFF_F 0
#define B_OFF_F (640*256)                        // 163840
#define XF_OFF_F (B_OFF_F + 1920*256)            // 655360
#define WF_OFF_BYTES ((XF_OFF_F + 600*4*256)*4)  // 5079040, 16B aligned

// ---------------- kernel 1: precompute A (sup@W1a + b1) and B (qry@W1b) ----------------
// grid = (40+120)*4 blocks: (cell, 64-col group). 512 threads.
// Stage the cell's 258x16 input in LDS; thread -> (col, 2 spatial n's).
__global__ void k1_rows(const float* __restrict__ sup, const float* __restrict__ qry,
                        const float* __restrict__ gw1, const float* __restrict__ gb1,
                        float* __restrict__ ws) {
    __shared__ float x[258 * 16];
    int bid = blockIdx.x;
    int cg = bid & 3;
    int cid = bid >> 2;
    bool isA = (cid < NB * NS);
    int cell = isA ? cid : (cid - NB * NS);
    const float* src = (isA ? sup : qry) + (size_t)cell * 4096;
    int t = threadIdx.x;
    ((float4*)x)[t] = ((const float4*)src)[t];
    ((float4*)x)[t + 512] = ((const float4*)src)[t + 512];
    if (t < 16) {
        x[256 * 16 + t] = (float)(t >> 2) * 0.25f;
        x[257 * 16 + t] = (float)(t & 3) * 0.25f;
    }
    __syncthreads();
    int col = cg * 64 + (t & 63);
    int ng = t >> 6;                 // n = ng*2, ng*2+1
    float binit = isA ? gb1[col] : 0.0f;
    float ax = binit, ay = binit;
    int koff = isA ? 0 : 258;
    #pragma unroll 4
    for (int k = 0; k < 258; ++k) {
        float wv = gw1[(size_t)(koff + k) * 256 + col];
        float2 xv = *(const float2*)(x + k * 16 + ng * 2);
        ax += xv.x * wv;
        ay += xv.y * wv;
    }
    float* dst = ws + (isA ? A_OFF_F : B_OFF_F) + ((size_t)cell * 16 + ng * 2) * 256 + col;
    dst[0] = ax;
    dst[256] = ay;
}

// ---------------- kernel 2: g_w2/3/4 -> bf16 fragment-linear, kk-major chunks ----------------
// chunk (L,kk) = 16 KB contiguous: frag idx = ((L*8 + kk)*16 + ntile)*64 + lane, 8 shorts.
// holds W[k][n], n = ntile*16 + (lane&15), k = kk*32 + (lane>>4)*8 + j
__global__ void k2_wfrag(const float* __restrict__ w2, const float* __restrict__ w3,
                         const float* __restrict__ w4, unsigned short* __restrict__ wf) {
    int bid = blockIdx.x;            // (L*8 + kk)*16 + ntile
    int L = bid >> 7;
    int kk = (bid >> 4) & 7;
    int ntile = bid & 15;
    int l = threadIdx.x;
    const float* W = (L == 0) ? w2 : ((L == 1) ? w3 : w4);
    int nn = ntile * 16 + (l & 15);
    int k0 = kk * 32 + (l >> 4) * 8;
    short8 ov;
    #pragma unroll
    for (int j = 0; j < 8; ++j)
        ov[j] = (short)f2bf(W[(size_t)(k0 + j) * 256 + nn]);
    *(short8*)(wf + ((size_t)bid * 64 + l) * 8) = ov;
}

// ---------------- kernel 3: g-MLP layers 2..4 + pair-sum ----------------
// grid = 600*2 blocks (bqs, 128-row half), 512 threads = 8 waves (2M x 4N).
// H: 64KB in-place, XOR-swizzled. Weights: LDS double-buffered 16KB kk-chunks,
// reg-staged (load early / ds_write late), one barrier per chunk.
__launch_bounds__(512, 2)
__global__ void k3_g(const float* __restrict__ wsA, const float* __restrict__ wsB,
                     const unsigned short* __restrict__ wf,
                     const float* __restrict__ gb2, const float* __restrict__ gb3,
                     const float* __restrict__ gb4, float* __restrict__ xf) {
    __shared__ short H[128 * 256];     // 64 KB
    __shared__ short Wb[2][8192];      // 2 x 16 KB weight chunks
    int bid = blockIdx.x;
    int bqs = bid >> 1, half = bid & 1;
    int b = bqs / 75, rem = bqs % 75, qi = rem / 5, si = rem % 5;
    int t = threadIdx.x;
    int l = t & 63;
    int wM = (t >> 6) >> 2, wN = (t >> 6) & 3;
    char* Hc = (char*)H;
    const char* wfc = (const char*)wf;

    // prefetch chunk 0 into regs (lands while phase 1 runs)
    short8 p0 = *(const short8*)(wfc + t * 16);
    short8 p1 = *(const short8*)(wfc + 8192 + t * 16);

    // ---- phase 1: H1[lr,c] = relu(A[n,c] + B[m,c]); global row = half*128+lr,
    // m = row>>4, n = row&15. Thread: 2 cols (c0,c0+1), 32 rows. Static reg indexing.
    {
        int tc = t & 127;                 // col pair index, byte offset 4*tc
        int rgrp = t >> 7;                // rows rgrp*32 .. +31
        const float2* Arow = (const float2*)(wsA + (size_t)(b * NS + si) * 4096) + tc;
        const float2* Brow = (const float2*)(wsB +
            ((size_t)(b * NQ + qi) * 16 + half * 8 + rgrp * 2) * 256) + tc;
        float2 Av[16];
        #pragma unroll
        for (int n = 0; n < 16; ++n) Av[n] = Arow[n * 128];
        float2 b0 = Brow[0], b1 = Brow[128];
        #pragma unroll
        for (int i = 0; i < 32; ++i) {
            int lr = rgrp * 32 + i;       // lr&15 == i&15, lr&7 == i&7 (rgrp*32 % 32 == 0)
            float2 a = Av[i & 15];
            float2 bb = (i < 16) ? b0 : b1;
            float lo = fmaxf(a.x + bb.x, 0.0f);
            float hi = fmaxf(a.y + bb.y, 0.0f);
            *(unsigned*)(Hc + lr * 512 + ((4 * tc) ^ ((i & 7) << 4))) = cvt_pk_bf16(lo, hi);
        }
    }
    // write chunk 0 into Wb[0]
    *(short8*)((char*)&Wb[0][0] + t * 16) = p0;
    *(short8*)((char*)&Wb[0][0] + 8192 + t * 16) = p1;
    __syncthreads();

    f32x4 acc[4][4];
    #pragma unroll
    for (int mm = 0; mm < 4; ++mm)
        #pragma unroll
        for (int tt = 0; tt < 4; ++tt)
            acc[mm][tt] = (f32x4){0.f, 0.f, 0.f, 0.f};

    int buf = 0;
    for (int c = 0; c < 24; ++c) {
        // issue next-chunk global loads early (hide under MFMA)
        short8 n0, n1;
        if (c < 23) {
            const char* src = wfc + (size_t)(c + 1) * 16384;
            n0 = *(const short8*)(src + t * 16);
            n1 = *(const short8*)(src + 8192 + t * 16);
        }
        // compute chunk c (kk = c&7): A from H, B from Wb[buf]
        int kk = c & 7;
        int kb = kk * 64 + (l >> 4) * 16;
        short8 af[4];
        #pragma unroll
        for (int mm = 0; mm < 4; ++mm) {
            int row = wM * 64 + mm * 16 + (l & 15);
            af[mm] = *(const short8*)(Hc + row * 512 + (kb ^ ((row & 7) << 4)));
        }
        char* Wc = (char*)&Wb[buf][0];
        #pragma unroll
        for (int tt = 0; tt < 4; ++tt) {
            short8 bv = *(const short8*)(Wc + ((wN * 4 + tt) * 64 + l) * 16);
            #pragma unroll
            for (int mm = 0; mm < 4; ++mm)
                acc[mm][tt] = __builtin_amdgcn_mfma_f32_16x16x32_bf16(
                    as_bf16x8(af[mm]), as_bf16x8(bv), acc[mm][tt], 0, 0, 0);
        }
        // stage next chunk into the idle buffer
        if (c < 23) {
            char* Wn = (char*)&Wb[buf ^ 1][0];
            *(short8*)(Wn + t * 16) = n0;
            *(short8*)(Wn + 8192 + t * 16) = n1;
        }
        if (kk == 7) {
            int L = c >> 3;
            __syncthreads();   // all H reads of this layer done
            const float* bias = (L == 0) ? gb2 : ((L == 1) ? gb3 : gb4);
            if (L < 2) {
                // relu(acc+bias) -> H in place (packed b32 via lane-pair shuffle)
                #pragma unroll
                for (int tt = 0; tt < 4; ++tt) {
                    int cc = wN * 64 + tt * 16 + (l & 15);
                    float bvv = bias[cc];
                    #pragma unroll
                    for (int mm = 0; mm < 4; ++mm) {
                        #pragma unroll
                        for (int r = 0; r < 4; ++r) {
                            int row = wM * 64 + mm * 16 + (l >> 4) * 4 + r;
                            float v = fmaxf(acc[mm][tt][r] + bvv, 0.0f);
                            float vh = __shfl_xor(v, 1);
                            if (!(l & 1))
                                *(unsigned*)(Hc + row * 512 + ((2 * cc) ^ ((row & 7) << 4))) =
                                    cvt_pk_bf16(v, vh);
                        }
                    }
                }
            } else {
                // layer 4: relu + column-sum over this wave's 64 rows -> xf slot
                #pragma unroll
                for (int tt = 0; tt < 4; ++tt) {
                    int cc = wN * 64 + tt * 16 + (l & 15);
                    float bvv = bias[cc];
                    float s = 0.0f;
                    #pragma unroll
                    for (int mm = 0; mm < 4; ++mm)
                        #pragma unroll
                        for (int r = 0; r < 4; ++r)
                            s += fmaxf(acc[mm][tt][r] + bvv, 0.0f);
                    s += __shfl_xor(s, 16);
                    s += __shfl_xor(s, 32);
                    if (l < 16)
                        xf[((size_t)bqs * 4 + half * 2 + wM) * 256 + wN * 64 + tt * 16 + l] = s;
                }
            }
            #pragma unroll
            for (int mm = 0; mm < 4; ++mm)
                #pragma unroll
                for (int tt = 0; tt < 4; ++tt)
                    acc[mm][tt] = (f32x4){0.f, 0.f, 0.f, 0.f};
        }
        __syncthreads();       // publishes epilogue writes + staged chunk c+1
        buf ^= 1;
    }
}

// ---------------- kernel 4: f-MLP + sigmoid + MSE loss ----------------
// grid = 150 blocks x 4 cells, 256 threads; fw loads reused 4x.
__global__ void k4_f(const float* __restrict__ xf,
                     const float* __restrict__ fw1, const float* __restrict__ fb1,
                     const float* __restrict__ fw2, const float* __restrict__ fb2,
                     const float* __restrict__ fw3, const float* __restrict__ fb3,
                     const float* __restrict__ fw4, const float* __restrict__ fb4,
                     const int* __restrict__ sy, const int* __restrict__ qy,
                     float* __restrict__ out) {
    __shared__ float xb[4][256], yb[4][256], y3[4][32];
    int base = blockIdx.x * 4;
    int t = threadIdx.x;
    #pragma unroll
    for (int c = 0; c < 4; ++c) {
        const float* xr = xf + (size_t)(base + c) * 1024 + t;
        xb[c][t] = xr[0] + xr[256] + xr[512] + xr[768];
    }
    __syncthreads();
    float acc[4];
    #pragma unroll
    for (int c = 0; c < 4; ++c) acc[c] = fb1[t];
    for (int k = 0; k < 256; ++k) {
        float wv = fw1[(size_t)k * 256 + t];
        #pragma unroll
        for (int c = 0; c < 4; ++c) acc[c] += xb[c][k] * wv;
    }
    #pragma unroll
    for (int c = 0; c < 4; ++c) yb[c][t] = acc[c] > 0.f ? acc[c] : 0.f;
    __syncthreads();
    #pragma unroll
    for (int c = 0; c < 4; ++c) acc[c] = fb2[t];
    for (int k = 0; k < 256; ++k) {
        float wv = fw2[(size_t)k * 256 + t];
        #pragma unroll
        for (int c = 0; c < 4; ++c) acc[c] += yb[c][k] * wv;
    }
    #pragma unroll
    for (int c = 0; c < 4; ++c) xb[c][t] = acc[c] > 0.f ? acc[c] : 0.f;
    __syncthreads();
    if (t < 116) {
        int c = t / 29, col = t % 29;
        float a = fb3[col];
        for (int k = 0; k < 256; ++k) a += xb[c][k] * fw3[(size_t)k * 29 + col];
        y3[c][col] = a > 0.f ? a : 0.f;
    }
    __syncthreads();
    if (t < 4) {
        int c = t;
        float z = fb4[0];
        for (int k = 0; k < 29; ++k) z += y3[c][k] * fw4[k];
        float score = 1.0f / (1.0f + __expf(-z));
        int bqs = base + c;
        int b = bqs / 75, rem = bqs % 75, qi = rem / 5, si = rem % 5;
        float label = (sy[b * NS + si] == qy[b * NQ + qi]) ? 1.0f : 0.0f;
        float d = label - score;
        atomicAdd(out, d * d * 0.125f);
    }
}

// ---------------- launch ----------------
extern "C" void kernel_launch(void* const* d_in, const int* in_sizes, int n_in,
                              void* d_out, int out_size, void* d_ws, size_t ws_size,
                              hipStream_t stream) {
    const float* sup = (const float*)d_in[0];
    const float* qry = (const float*)d_in[1];
    const int*   sy  = (const int*)d_in[2];
    const int*   qy  = (const int*)d_in[3];
    const float* gw1 = (const float*)d_in[4];
    const float* gb1 = (const float*)d_in[5];
    const float* gw2 = (const float*)d_in[6];
    const float* gb2 = (const float*)d_in[7];
    const float* gw3 = (const float*)d_in[8];
    const float* gb3 = (const float*)d_in[9];
    const float* gw4 = (const float*)d_in[10];
    const float* gb4 = (const float*)d_in[11];
    const float* fw1 = (const float*)d_in[12];
    const float* fb1 = (const float*)d_in[13];
    const float* fw2 = (const float*)d_in[14];
    const float* fb2 = (const float*)d_in[15];
    const float* fw3 = (const float*)d_in[16];
    const float* fb3 = (const float*)d_in[17];
    const float* fw4 = (const float*)d_in[18];
    const float* fb4 = (const float*)d_in[19];

    float* ws = (float*)d_ws;
    float* A  = ws + A_OFF_F;
    float* B  = ws + B_OFF_F;
    float* xf = ws + XF_OFF_F;
    unsigned short* wf = (unsigned short*)((char*)d_ws + WF_OFF_BYTES);
    float* out = (float*)d_out;

    hipMemsetAsync(out, 0, sizeof(float), stream);

    k1_rows<<<(NB * NS + NB * NQ) * 4, 512, 0, stream>>>(sup, qry, gw1, gb1, ws);
    k2_wfrag<<<384, 64, 0, stream>>>(gw2, gw3, gw4, wf);
    k3_g<<<600 * 2, 512, 0, stream>>>(A, B, wf, gb2, gb3, gb4, xf);
    k4_f<<<150, 256, 0, stream>>>(xf, fw1, fb1, fw2, fb2, fw3, fb3, fw4, fb4, sy, qy, out);
}

// Round 4
// 173.846 us; speedup vs baseline: 2.6651x; 1.0604x over previous
//
#include <hip/hip_runtime.h>

// ---------------- types / helpers ----------------
typedef __attribute__((ext_vector_type(8))) __bf16 bf16x8;
typedef __attribute__((ext_vector_type(8))) short short8;
typedef __attribute__((ext_vector_type(4))) float f32x4;

static __device__ __forceinline__ unsigned short f2bf(float f) {
    unsigned u = __float_as_uint(f);
    u += 0x7FFFu + ((u >> 16) & 1u);
    return (unsigned short)(u >> 16);
}
static __device__ __forceinline__ unsigned cvt_pk_bf16(float lo, float hi) {
    unsigned r;
    asm("v_cvt_pk_bf16_f32 %0, %1, %2" : "=v"(r) : "v"(lo), "v"(hi));
    return r;
}
static __device__ __forceinline__ bf16x8 as_bf16x8(short8 v) {
    return __builtin_bit_cast(bf16x8, v);
}
static __device__ __forceinline__ f32x4 mfma16(short8 a, short8 b, f32x4 c) {
    return __builtin_amdgcn_mfma_f32_16x16x32_bf16(as_bf16x8(a), as_bf16x8(b), c, 0, 0, 0);
}

// problem sizes
#define NB 8
#define NS 5
#define NQ 15
// ws layout (in floats)
#define A_OFF_F 0
#define B_OFF_F (640*256)                        // 163840
#define XF_OFF_F (B_OFF_F + 1920*256)            // 655360
#define WF_OFF_BYTES ((XF_OFF_F + 600*4*256)*4)  // 5079040, 16B aligned

// ---------------- kernel 1: precompute A (sup@W1a + b1) and B (qry@W1b) ----------------
__global__ void k1_rows(const float* __restrict__ sup, const float* __restrict__ qry,
                        const float* __restrict__ gw1, const float* __restrict__ gb1,
                        float* __restrict__ ws) {
    __shared__ float x[258 * 16];
    int bid = blockIdx.x;
    int cg = bid & 3;
    int cid = bid >> 2;
    bool isA = (cid < NB * NS);
    int cell = isA ? cid : (cid - NB * NS);
    const float* src = (isA ? sup : qry) + (size_t)cell * 4096;
    int t = threadIdx.x;
    ((float4*)x)[t] = ((const float4*)src)[t];
    ((float4*)x)[t + 512] = ((const float4*)src)[t + 512];
    if (t < 16) {
        x[256 * 16 + t] = (float)(t >> 2) * 0.25f;
        x[257 * 16 + t] = (float)(t & 3) * 0.25f;
    }
    __syncthreads();
    int col = cg * 64 + (t & 63);
    int ng = t >> 6;                 // n = ng*2, ng*2+1
    float binit = isA ? gb1[col] : 0.0f;
    float ax = binit, ay = binit;
    int koff = isA ? 0 : 258;
    #pragma unroll 4
    for (int k = 0; k < 258; ++k) {
        float wv = gw1[(size_t)(koff + k) * 256 + col];
        float2 xv = *(const float2*)(x + k * 16 + ng * 2);
        ax += xv.x * wv;
        ay += xv.y * wv;
    }
    float* dst = ws + (isA ? A_OFF_F : B_OFF_F) + ((size_t)cell * 16 + ng * 2) * 256 + col;
    dst[0] = ax;
    dst[256] = ay;
}

// ---------------- kernel 2: g_w2/3/4 -> bf16 A-frag-linear, (L,tt,kk) chunk order ----------------
// frag (L,tt,kk) at byte ((L*16+tt)*8+kk)*1024; lane l holds
// W[k = kk*32+(l>>4)*8+j][outcol = tt*16+(l&15)], j=0..7.
__global__ void k2_wfrag(const float* __restrict__ w2, const float* __restrict__ w3,
                         const float* __restrict__ w4, unsigned short* __restrict__ wf) {
    int bid = blockIdx.x;            // ((L*16 + tt)*8 + kk)
    int L = bid >> 7;
    int tt = (bid >> 3) & 15;
    int kk = bid & 7;
    int l = threadIdx.x;
    const float* W = (L == 0) ? w2 : ((L == 1) ? w3 : w4);
    int nn = tt * 16 + (l & 15);
    int k0 = kk * 32 + (l >> 4) * 8;
    short8 ov;
    #pragma unroll
    for (int j = 0; j < 8; ++j)
        ov[j] = (short)f2bf(W[(size_t)(k0 + j) * 256 + nn]);
    *(short8*)(wf + ((size_t)bid * 64 + l) * 8) = ov;
}

// ---------------- kernel 3: g-MLP layers 2..4 + pair-sum (swapped MFMA, no barriers) ------
// grid = 600 blocks (one cell = 256 pairs), 256 threads = 4 waves x 64 pairs.
// H in LDS (128 KB) in B-frag-linear layout, wave-private slices.
// W streamed global->regs, double-buffered 8KB (one tt) chunks.
#define EPI_W(PG, ACC)                                                          \
    {                                                                           \
        float v0 = fmaxf(ACC[0] + bv.x, 0.f);                                   \
        float v1 = fmaxf(ACC[1] + bv.y, 0.f);                                   \
        float v2 = fmaxf(ACC[2] + bv.z, 0.f);                                   \
        float v3 = fmaxf(ACC[3] + bv.w, 0.f);                                   \
        char* ad = Hb + (size_t)((w4_ + PG) * 8 + kk2) * 1024 + wb;             \
        *(unsigned*)ad = cvt_pk_bf16(v0, v1);                                   \
        *(unsigned*)(ad + 4) = cvt_pk_bf16(v2, v3);                             \
    }

#define TT_BODY(WCUR, WOTHER)                                                   \
    {                                                                           \
        int nidx = chunk + 1; if (nidx > 47) nidx = 47;                         \
        const char* nsrc = wfb + (size_t)nidx * 8192 + l * 16;                  \
        _Pragma("unroll")                                                       \
        for (int kk = 0; kk < 8; ++kk)                                          \
            WOTHER[kk] = *(const short8*)(nsrc + kk * 1024);                    \
        f32x4 acc0 = {0.f,0.f,0.f,0.f}, acc1 = {0.f,0.f,0.f,0.f};               \
        f32x4 acc2 = {0.f,0.f,0.f,0.f}, acc3 = {0.f,0.f,0.f,0.f};               \
        _Pragma("unroll")                                                       \
        for (int kk = 0; kk < 8; ++kk) {                                        \
            acc0 = mfma16(WCUR[kk], bfr[0][kk], acc0);                          \
            acc1 = mfma16(WCUR[kk], bfr[1][kk], acc1);                          \
            acc2 = mfma16(WCUR[kk], bfr[2][kk], acc2);                          \
            acc3 = mfma16(WCUR[kk], bfr[3][kk], acc3);                          \
        }                                                                       \
        float4 bv = *(const float4*)(bias + tt * 16 + g * 4);                   \
        if (L < 2) {                                                            \
            int kk2 = tt >> 1;                                                  \
            int sub = (2 * tt + (g >> 1)) & 3;                                  \
            int wb = (c + 16 * sub) * 16 + (g & 1) * 8;                         \
            EPI_W(0, acc0) EPI_W(1, acc1) EPI_W(2, acc2) EPI_W(3, acc3)         \
        } else {                                                                \
            float s0 = fmaxf(acc0[0]+bv.x,0.f)+fmaxf(acc1[0]+bv.x,0.f)          \
                     + fmaxf(acc2[0]+bv.x,0.f)+fmaxf(acc3[0]+bv.x,0.f);         \
            float s1 = fmaxf(acc0[1]+bv.y,0.f)+fmaxf(acc1[1]+bv.y,0.f)          \
                     + fmaxf(acc2[1]+bv.y,0.f)+fmaxf(acc3[1]+bv.y,0.f);         \
            float s2 = fmaxf(acc0[2]+bv.z,0.f)+fmaxf(acc1[2]+bv.z,0.f)          \
                     + fmaxf(acc2[2]+bv.z,0.f)+fmaxf(acc3[2]+bv.z,0.f);         \
            float s3 = fmaxf(acc0[3]+bv.w,0.f)+fmaxf(acc1[3]+bv.w,0.f)          \
                     + fmaxf(acc2[3]+bv.w,0.f)+fmaxf(acc3[3]+bv.w,0.f);         \
            s0 += __shfl_xor(s0,1); s0 += __shfl_xor(s0,2);                     \
            s0 += __shfl_xor(s0,4); s0 += __shfl_xor(s0,8);                     \
            s1 += __shfl_xor(s1,1); s1 += __shfl_xor(s1,2);                     \
            s1 += __shfl_xor(s1,4); s1 += __shfl_xor(s1,8);                     \
            s2 += __shfl_xor(s2,1); s2 += __shfl_xor(s2,2);                     \
            s2 += __shfl_xor(s2,4); s2 += __shfl_xor(s2,8);                     \
            s3 += __shfl_xor(s3,1); s3 += __shfl_xor(s3,2);                     \
            s3 += __shfl_xor(s3,4); s3 += __shfl_xor(s3,8);                     \
            if (c == 0) {                                                       \
                float4 o = {s0, s1, s2, s3};                                    \
                *(float4*)(xf + (size_t)(bqs * 4 + w) * 256 + tt * 16 + g * 4) = o; \
            }                                                                   \
        }                                                                       \
        ++chunk;                                                                \
    }

__launch_bounds__(256, 1)
__global__ void k3_g(const float* __restrict__ wsA, const float* __restrict__ wsB,
                     const unsigned short* __restrict__ wf,
                     const float* __restrict__ gb2, const float* __restrict__ gb3,
                     const float* __restrict__ gb4, float* __restrict__ xf) {
    __shared__ short Hf[65536];   // 128 KB: frag(pgg,kk) at (pgg*8+kk)*1024 bytes
    int bqs = blockIdx.x;
    int b = bqs / 75, rem = bqs % 75, qi = rem / 5, si = rem % 5;
    int t = threadIdx.x;
    int w = t >> 6, l = t & 63;
    int g = l >> 4, c = l & 15;
    int w4_ = w * 4;
    char* Hb = (char*)Hf;
    const char* wfb = (const char*)wf;

    // W chunk 0 prologue (lands under phase 1)
    short8 wA[8], wB[8];
    #pragma unroll
    for (int kk = 0; kk < 8; ++kk)
        wA[kk] = *(const short8*)(wfb + kk * 1024 + l * 16);

    // ---- phase 1: H1[pair][k] = relu(A[n][k] + B[m][k]) straight into B-frag layout.
    // pair = (w4_+pg)*16 + c  ->  n = c, m = w4_+pg; k = kk*32 + g*8 + j.
    {
        const float* Arow = wsA + (size_t)(b * NS + si) * 4096;
        const float* Brow = wsB + (size_t)(b * NQ + qi) * 4096;
        #pragma unroll
        for (int pg = 0; pg < 4; ++pg) {
            int m = w4_ + pg;
            #pragma unroll
            for (int kk = 0; kk < 8; ++kk) {
                const float* ap = Arow + c * 256 + kk * 32 + g * 8;
                const float* bp = Brow + m * 256 + kk * 32 + g * 8;
                float4 a0 = *(const float4*)ap, a1 = *(const float4*)(ap + 4);
                float4 b0 = *(const float4*)bp, b1 = *(const float4*)(bp + 4);
                unsigned u0 = cvt_pk_bf16(fmaxf(a0.x + b0.x, 0.f), fmaxf(a0.y + b0.y, 0.f));
                unsigned u1 = cvt_pk_bf16(fmaxf(a0.z + b0.z, 0.f), fmaxf(a0.w + b0.w, 0.f));
                unsigned u2 = cvt_pk_bf16(fmaxf(a1.x + b1.x, 0.f), fmaxf(a1.y + b1.y, 0.f));
                unsigned u3 = cvt_pk_bf16(fmaxf(a1.z + b1.z, 0.f), fmaxf(a1.w + b1.w, 0.f));
                uint4 hv = {u0, u1, u2, u3};
                *(uint4*)(Hb + (size_t)(m * 8 + kk) * 1024 + l * 16) = hv;
            }
        }
    }
    // no __syncthreads needed anywhere: each wave's 64 pairs are private.

    int chunk = 0;
    #pragma unroll 1
    for (int L = 0; L < 3; ++L) {
        const float* bias = (L == 0) ? gb2 : ((L == 1) ? gb3 : gb4);
        // load this layer's H fragments into registers (own pairs only)
        short8 bfr[4][8];
        #pragma unroll
        for (int pg = 0; pg < 4; ++pg)
            #pragma unroll
            for (int kk = 0; kk < 8; ++kk)
                bfr[pg][kk] = *(const short8*)(Hb + (size_t)((w4_ + pg) * 8 + kk) * 1024 + l * 16);
        #pragma unroll 1
        for (int tt2 = 0; tt2 < 8; ++tt2) {
            int tt = tt2 * 2;
            TT_BODY(wA, wB)
            tt = tt2 * 2 + 1;
            TT_BODY(wB, wA)
        }
    }
}

// ---------------- kernel 4: f-MLP + sigmoid + MSE loss ----------------
__global__ void k4_f(const float* __restrict__ xf,
                     const float* __restrict__ fw1, const float* __restrict__ fb1,
                     const float* __restrict__ fw2, const float* __restrict__ fb2,
                     const float* __restrict__ fw3, const float* __restrict__ fb3,
                     const float* __restrict__ fw4, const float* __restrict__ fb4,
                     const int* __restrict__ sy, const int* __restrict__ qy,
                     float* __restrict__ out) {
    __shared__ float xb[4][256], yb[4][256], y3[4][32];
    int base = blockIdx.x * 4;
    int t = threadIdx.x;
    #pragma unroll
    for (int c = 0; c < 4; ++c) {
        const float* xr = xf + (size_t)(base + c) * 1024 + t;
        xb[c][t] = xr[0] + xr[256] + xr[512] + xr[768];
    }
    __syncthreads();
    float acc[4];
    #pragma unroll
    for (int c = 0; c < 4; ++c) acc[c] = fb1[t];
    for (int k = 0; k < 256; ++k) {
        float wv = fw1[(size_t)k * 256 + t];
        #pragma unroll
        for (int c = 0; c < 4; ++c) acc[c] += xb[c][k] * wv;
    }
    #pragma unroll
    for (int c = 0; c < 4; ++c) yb[c][t] = acc[c] > 0.f ? acc[c] : 0.f;
    __syncthreads();
    #pragma unroll
    for (int c = 0; c < 4; ++c) acc[c] = fb2[t];
    for (int k = 0; k < 256; ++k) {
        float wv = fw2[(size_t)k * 256 + t];
        #pragma unroll
        for (int c = 0; c < 4; ++c) acc[c] += yb[c][k] * wv;
    }
    #pragma unroll
    for (int c = 0; c < 4; ++c) xb[c][t] = acc[c] > 0.f ? acc[c] : 0.f;
    __syncthreads();
    if (t < 116) {
        int c = t / 29, col = t % 29;
        float a = fb3[col];
        for (int k = 0; k < 256; ++k) a += xb[c][k] * fw3[(size_t)k * 29 + col];
        y3[c][col] = a > 0.f ? a : 0.f;
    }
    __syncthreads();
    if (t < 4) {
        int c = t;
        float z = fb4[0];
        for (int k = 0; k < 29; ++k) z += y3[c][k] * fw4[k];
        float score = 1.0f / (1.0f + __expf(-z));
        int bqs = base + c;
        int b = bqs / 75, rem = bqs % 75, qi = rem / 5, si = rem % 5;
        float label = (sy[b * NS + si] == qy[b * NQ + qi]) ? 1.0f : 0.0f;
        float d = label - score;
        atomicAdd(out, d * d * 0.125f);
    }
}

// ---------------- launch ----------------
extern "C" void kernel_launch(void* const* d_in, const int* in_sizes, int n_in,
                              void* d_out, int out_size, void* d_ws, size_t ws_size,
                              hipStream_t stream) {
    const float* sup = (const float*)d_in[0];
    const float* qry = (const float*)d_in[1];
    const int*   sy  = (const int*)d_in[2];
    const int*   qy  = (const int*)d_in[3];
    const float* gw1 = (const float*)d_in[4];
    const float* gb1 = (const float*)d_in[5];
    const float* gw2 = (const float*)d_in[6];
    const float* gb2 = (const float*)d_in[7];
    const float* gw3 = (const float*)d_in[8];
    const float* gb3 = (const float*)d_in[9];
    const float* gw4 = (const float*)d_in[10];
    const float* gb4 = (const float*)d_in[11];
    const float* fw1 = (const float*)d_in[12];
    const float* fb1 = (const float*)d_in[13];
    const float* fw2 = (const float*)d_in[14];
    const float* fb2 = (const float*)d_in[15];
    const float* fw3 = (const float*)d_in[16];
    const float* fb3 = (const float*)d_in[17];
    const float* fw4 = (const float*)d_in[18];
    const float* fb4 = (const float*)d_in[19];

    float* ws = (float*)d_ws;
    float* A  = ws + A_OFF_F;
    float* B  = ws + B_OFF_F;
    float* xf = ws + XF_OFF_F;
    unsigned short* wf = (unsigned short*)((char*)d_ws + WF_OFF_BYTES);
    float* out = (float*)d_out;

    hipMemsetAsync(out, 0, sizeof(float), stream);

    k1_rows<<<(NB * NS + NB * NQ) * 4, 512, 0, stream>>>(sup, qry, gw1, gb1, ws);
    k2_wfrag<<<384, 64, 0, stream>>>(gw2, gw3, gw4, wf);
    k3_g<<<600, 256, 0, stream>>>(A, B, wf, gb2, gb3, gb4, xf);
    k4_f<<<150, 256, 0, stream>>>(xf, fw1, fb1, fw2, fb2, fw3, fb3, fw4, fb4, sy, qy, out);
}